// Round 1
// 1243.061 us; speedup vs baseline: 1.0573x; 1.0573x over previous
//
#include <hip/hip_runtime.h>
#include <stdint.h>

#define V_ 32000
#define E_ 512
#define H_ 1024
#define B_ 16
#define S_ 128
#define K_ 15

typedef float floatx4 __attribute__((ext_vector_type(4)));
typedef short shortx8 __attribute__((ext_vector_type(8)));
typedef __bf16 bf16x8 __attribute__((ext_vector_type(8)));

static __device__ __forceinline__ unsigned short f2b(float f) {
  union { float f; uint32_t u; } v; v.f = f;
  uint32_t u = v.u;
  u += 0x7FFFu + ((u >> 16) & 1u);   // round-to-nearest-even
  return (unsigned short)(u >> 16);
}

static __device__ __forceinline__ shortx8 cvt8(floatx4 a, floatx4 b) {
  shortx8 r;
  r[0] = (short)f2b(a[0]); r[1] = (short)f2b(a[1]);
  r[2] = (short)f2b(a[2]); r[3] = (short)f2b(a[3]);
  r[4] = (short)f2b(b[0]); r[5] = (short)f2b(b[1]);
  r[6] = (short)f2b(b[2]); r[7] = (short)f2b(b[3]);
  return r;
}

static __device__ __forceinline__ floatx4 mfma_bf16(shortx8 a, shortx8 b, floatx4 c) {
  return __builtin_amdgcn_mfma_f32_16x16x32_bf16(
      __builtin_bit_cast(bf16x8, a), __builtin_bit_cast(bf16x8, b), c, 0, 0, 0);
}

// ---------------- tiny kernels ----------------

__global__ void k_zero(int* __restrict__ p, int n) {
  int i = blockIdx.x * blockDim.x + threadIdx.x;
  if (i < n) p[i] = 0;
}

// topic[n] = sum_k theta[k] * beta[k][n]   (grid 125x256 == 32000 exactly)
__global__ void k_topic(const float* __restrict__ beta, const float* __restrict__ theta,
                        float* __restrict__ topic) {
  int n = blockIdx.x * blockDim.x + threadIdx.x;
  float s = 0.f;
#pragma unroll
  for (int k = 0; k < K_; ++k) s += theta[k] * beta[k * V_ + n];
  topic[n] = s;
}

// fp32 -> bf16, 8 elems/thread. grid*block*8 must equal n exactly.
__global__ void k_cvt(const float* __restrict__ src, unsigned short* __restrict__ dst) {
  size_t i = (size_t)(blockIdx.x * blockDim.x + threadIdx.x) * 8;
  floatx4 f0 = *(const floatx4*)(src + i);
  floatx4 f1 = *(const floatx4*)(src + i + 4);
  *(shortx8*)(dst + i) = cvt8(f0, f1);
}

// ---------------- pre-projection GEMM ----------------
// pre[m=t*16+b][n] = sum_e W_emb[ids[b][t]][e]*W_ih[n][e] + b_ih[n] + b_hh[n]
// M=2048, N=1024, K=512. grid (N/128=8, M/128=16), 256 threads.
__global__ __launch_bounds__(256, 2) void k_gemm_pre(
    const int* __restrict__ ids, const float* __restrict__ W_emb,
    const float* __restrict__ W_ih, const float* __restrict__ b_ih,
    const float* __restrict__ b_hh, float* __restrict__ pre) {
  __shared__ unsigned short As[128 * 72];
  __shared__ unsigned short Bs[128 * 72];
  const int tid = threadIdx.x;
  const int gn0 = blockIdx.x * 128;
  const int gm0 = blockIdx.y * 128;
  const int wave = tid >> 6, lane = tid & 63;
  const int wm = (wave >> 1) * 64, wn = (wave & 1) * 64;
  const int lr = lane & 15, lg = lane >> 4;

  floatx4 acc[4][4];
#pragma unroll
  for (int i = 0; i < 4; ++i)
#pragma unroll
    for (int j = 0; j < 4; ++j) acc[i][j] = (floatx4)0.0f;

  for (int k0 = 0; k0 < E_; k0 += 64) {
#pragma unroll
    for (int c = 0; c < 4; ++c) {
      int q = c * 256 + tid;
      int row = q >> 3, kc = (q & 7) * 8;
      int m = gm0 + row;
      int id = ids[(m & 15) * S_ + (m >> 4)];
      const float* ga = W_emb + (size_t)id * E_ + k0 + kc;
      floatx4 a0 = *(const floatx4*)ga;
      floatx4 a1 = *(const floatx4*)(ga + 4);
      *(shortx8*)&As[row * 72 + kc] = cvt8(a0, a1);
      const float* gb = W_ih + (size_t)(gn0 + row) * E_ + k0 + kc;
      floatx4 c0 = *(const floatx4*)gb;
      floatx4 c1 = *(const floatx4*)(gb + 4);
      *(shortx8*)&Bs[row * 72 + kc] = cvt8(c0, c1);
    }
    __syncthreads();
#pragma unroll
    for (int ks = 0; ks < 64; ks += 32) {
      shortx8 af[4], bfr[4];
#pragma unroll
      for (int i = 0; i < 4; ++i)
        af[i] = *(const shortx8*)&As[(wm + i * 16 + lr) * 72 + ks + lg * 8];
#pragma unroll
      for (int j = 0; j < 4; ++j)
        bfr[j] = *(const shortx8*)&Bs[(wn + j * 16 + lr) * 72 + ks + lg * 8];
#pragma unroll
      for (int i = 0; i < 4; ++i)
#pragma unroll
        for (int j = 0; j < 4; ++j) acc[i][j] = mfma_bf16(af[i], bfr[j], acc[i][j]);
    }
    __syncthreads();
  }
#pragma unroll
  for (int i = 0; i < 4; ++i) {
#pragma unroll
    for (int r = 0; r < 4; ++r) {
      int m = gm0 + wm + i * 16 + lg * 4 + r;
#pragma unroll
      for (int j = 0; j < 4; ++j) {
        int n = gn0 + wn + j * 16 + lr;
        pre[(size_t)m * H_ + n] = acc[i][j][r] + b_ih[n] + b_hh[n];
      }
    }
  }
}

// ---------------- persistent RNN kernel (16 blocks x 256) ----------------
// Each block owns 64 output columns; each wave owns 16 columns with the FULL
// K=1024 (no K-split => no LDS reduction, no intra-loop __syncthreads pair).
// W_hh fragments live in 128 VGPRs per wave for all 128 steps.
// h is exchanged in fragment-linear layout so A-fragment loads are a single
// coalesced dwordx4 per k-step: elem (b,n) at ((n>>5)*64+((n>>3)&3)*16+b)*8+(n&7).
// Barrier: 16 participants, one counter per step padded to 128 B.
__global__ __launch_bounds__(256, 1) void k_rnn(
    const float* __restrict__ hidden0, const float* __restrict__ W_hh,
    const float* __restrict__ pre, unsigned short* __restrict__ hb,  // [2][16*1024] bf16 frag-linear
    unsigned short* __restrict__ act,  // [b*128+t][1024] bf16
    float* __restrict__ hT_out,        // [16][1024] fp32 (d_out tail)
    int* __restrict__ bar) {
  const int tid = threadIdx.x, bid = blockIdx.x;
  const int lane = tid & 63, wave = tid >> 6;
  const int lr = lane & 15, lg = lane >> 4;
  const int nn = bid * 64 + wave * 16 + lr;  // this lane's output column

  // W_hh fragments -> registers, held across all steps.
  // B-frag for kstep s: lane holds B[k=s*32+lg*8 .. +8][col=lr] = W_hh[nn][k..k+8]
  shortx8 bfr[32];
#pragma unroll
  for (int s = 0; s < 32; ++s) {
    const float* g = W_hh + (size_t)nn * H_ + s * 32 + lg * 8;
    floatx4 f0 = *(const floatx4*)g;
    floatx4 f1 = *(const floatx4*)(g + 4);
    bfr[s] = cvt8(f0, f1);
  }

  // h0 -> hb[0] fragment-linear bf16 (4 elems/thread over 16 blocks x 256)
  {
    int gt = (bid * 256 + tid) * 4;
#pragma unroll
    for (int u = 0; u < 4; ++u) {
      int e = gt + u;
      int b = e >> 10, n = e & 1023;
      hb[(((n >> 5) * 64 + ((n >> 3) & 3) * 16 + b) << 3) + (n & 7)] = f2b(hidden0[e]);
    }
  }

  __syncthreads();
  if (tid == 0) {
    __threadfence();
    __hip_atomic_fetch_add(&bar[0], 1, __ATOMIC_ACQ_REL, __HIP_MEMORY_SCOPE_AGENT);
    while (__hip_atomic_load(&bar[0], __ATOMIC_ACQUIRE, __HIP_MEMORY_SCOPE_AGENT) < 16)
      __builtin_amdgcn_s_sleep(1);
  }
  __syncthreads();

  // fragment-linear store base for this lane's column nn (add b*8 per row)
  const int sft = (((nn >> 5) * 64 + ((nn >> 3) & 3) * 16) << 3) + (nn & 7);

  for (int t = 0; t < S_; ++t) {
    const unsigned short* hcur = hb + (t & 1) * (B_ * H_);
    unsigned short* hnxt = hb + ((t + 1) & 1) * (B_ * H_);

    // pre for this step (independent of h; issues immediately)
    float prer[4];
#pragma unroll
    for (int r = 0; r < 4; ++r)
      prer[r] = pre[((size_t)t * B_ + lg * 4 + r) * H_ + nn];

    // 32 MFMAs over full K, 4 interleaved accumulators (dep distance 4)
    floatx4 a0 = (floatx4)0.f, a1 = (floatx4)0.f, a2 = (floatx4)0.f, a3 = (floatx4)0.f;
#pragma unroll
    for (int s = 0; s < 32; s += 4) {
      shortx8 f0 = *(const shortx8*)&hcur[((s + 0) * 64 + lane) * 8];
      shortx8 f1 = *(const shortx8*)&hcur[((s + 1) * 64 + lane) * 8];
      shortx8 f2 = *(const shortx8*)&hcur[((s + 2) * 64 + lane) * 8];
      shortx8 f3 = *(const shortx8*)&hcur[((s + 3) * 64 + lane) * 8];
      a0 = mfma_bf16(f0, bfr[s + 0], a0);
      a1 = mfma_bf16(f1, bfr[s + 1], a1);
      a2 = mfma_bf16(f2, bfr[s + 2], a2);
      a3 = mfma_bf16(f3, bfr[s + 3], a3);
    }
    floatx4 acc = (a0 + a1) + (a2 + a3);

    // C/D: row b = lg*4 + r, col = nn
#pragma unroll
    for (int r = 0; r < 4; ++r) {
      int b = lg * 4 + r;
      float h = tanhf(acc[r] + prer[r]);
      unsigned short h16 = f2b(h);
      hnxt[sft + b * 8] = h16;
      act[((size_t)b * S_ + t) * H_ + nn] = h16;
      if (t == S_ - 1) hT_out[b * H_ + nn] = h;
    }

    if (t < S_ - 1) {
      __syncthreads();
      if (tid == 0) {
        __threadfence();
        __hip_atomic_fetch_add(&bar[(t + 1) * 32], 1, __ATOMIC_ACQ_REL,
                               __HIP_MEMORY_SCOPE_AGENT);
        while (__hip_atomic_load(&bar[(t + 1) * 32], __ATOMIC_ACQUIRE,
                                 __HIP_MEMORY_SCOPE_AGENT) < 16)
          __builtin_amdgcn_s_sleep(1);
      }
      __syncthreads();
    }
  }
}

// ---------------- decoder GEMM ----------------
// out[m][n] = act[m]·Wdec[n] + b_dec[n] + topic[n]*(stop[m]==0)
// M=2048, N=32000, K=1024. grid (250, 16), 256 threads.
__global__ __launch_bounds__(256, 2) void k_gemm_dec(
    const unsigned short* __restrict__ A, const unsigned short* __restrict__ Bw,
    const float* __restrict__ b_dec, const float* __restrict__ topic,
    const int* __restrict__ stop, float* __restrict__ out) {
  __shared__ unsigned short As[128 * 72];
  __shared__ unsigned short Bs[128 * 72];
  const int tid = threadIdx.x;
  const int gn0 = blockIdx.x * 128;
  const int gm0 = blockIdx.y * 128;
  const int wave = tid >> 6, lane = tid & 63;
  const int wm = (wave >> 1) * 64, wn = (wave & 1) * 64;
  const int lr = lane & 15, lg = lane >> 4;

  floatx4 acc[4][4];
#pragma unroll
  for (int i = 0; i < 4; ++i)
#pragma unroll
    for (int j = 0; j < 4; ++j) acc[i][j] = (floatx4)0.0f;

  for (int k0 = 0; k0 < H_; k0 += 64) {
#pragma unroll
    for (int c = 0; c < 4; ++c) {
      int q = c * 256 + tid;
      int row = q >> 3, kc = (q & 7) * 8;
      *(shortx8*)&As[row * 72 + kc] =
          *(const shortx8*)(A + (size_t)(gm0 + row) * H_ + k0 + kc);
      *(shortx8*)&Bs[row * 72 + kc] =
          *(const shortx8*)(Bw + (size_t)(gn0 + row) * H_ + k0 + kc);
    }
    __syncthreads();
#pragma unroll
    for (int ks = 0; ks < 64; ks += 32) {
      shortx8 af[4], bfr[4];
#pragma unroll
      for (int i = 0; i < 4; ++i)
        af[i] = *(const shortx8*)&As[(wm + i * 16 + lr) * 72 + ks + lg * 8];
#pragma unroll
      for (int j = 0; j < 4; ++j)
        bfr[j] = *(const shortx8*)&Bs[(wn + j * 16 + lr) * 72 + ks + lg * 8];
#pragma unroll
      for (int i = 0; i < 4; ++i)
#pragma unroll
        for (int j = 0; j < 4; ++j) acc[i][j] = mfma_bf16(af[i], bfr[j], acc[i][j]);
    }
    __syncthreads();
  }
#pragma unroll
  for (int i = 0; i < 4; ++i) {
#pragma unroll
    for (int r = 0; r < 4; ++r) {
      int m = gm0 + wm + i * 16 + lg * 4 + r;
      float msk = (stop[m] == 0) ? 1.f : 0.f;
      size_t base = (size_t)m * V_;
#pragma unroll
      for (int j = 0; j < 4; ++j) {
        int n = gn0 + wn + j * 16 + lr;
        out[base + n] = acc[i][j][r] + b_dec[n] + topic[n] * msk;
      }
    }
  }
}

// ---------------- launcher ----------------
extern "C" void kernel_launch(void* const* d_in, const int* in_sizes, int n_in,
                              void* d_out, int out_size, void* d_ws, size_t ws_size,
                              hipStream_t stream) {
  (void)in_sizes; (void)n_in; (void)out_size; (void)ws_size;
  const int*   ids    = (const int*)d_in[0];
  const float* hidden = (const float*)d_in[1];
  const int*   stop   = (const int*)d_in[2];
  const float* W_emb  = (const float*)d_in[3];
  const float* W_ih   = (const float*)d_in[4];
  const float* b_ih   = (const float*)d_in[5];
  const float* W_hh   = (const float*)d_in[6];
  const float* b_hh   = (const float*)d_in[7];
  const float* W_dec  = (const float*)d_in[8];
  const float* b_dec  = (const float*)d_in[9];
  const float* beta   = (const float*)d_in[10];
  const float* theta  = (const float*)d_in[11];
  float* out = (float*)d_out;

  char* ws = (char*)d_ws;
  size_t off = 0;
  auto alloc = [&](size_t bytes) -> void* {
    void* p = ws + off;
    off = (off + bytes + 255) & ~(size_t)255;
    return p;
  };
  int* bar = (int*)alloc(16384 * sizeof(int));   // (S_+1) counters @128B stride
  float* topic = (float*)alloc((size_t)V_ * 4);
  float* pre = (float*)alloc((size_t)B_ * S_ * H_ * 4);
  unsigned short* act = (unsigned short*)alloc((size_t)B_ * S_ * H_ * 2);
  unsigned short* hb = (unsigned short*)alloc((size_t)2 * B_ * H_ * 2);
  unsigned short* wdec16 = (unsigned short*)alloc((size_t)V_ * H_ * 2);

  k_zero<<<dim3(32), dim3(512), 0, stream>>>(bar, 16384);
  k_topic<<<dim3(V_ / 256), dim3(256), 0, stream>>>(beta, theta, topic);
  k_cvt<<<dim3((V_ * H_) / (256 * 8)), dim3(256), 0, stream>>>(W_dec, wdec16);
  k_gemm_pre<<<dim3(H_ / 128, (B_ * S_) / 128), dim3(256), 0, stream>>>(
      ids, W_emb, W_ih, b_ih, b_hh, pre);
  k_rnn<<<dim3(16), dim3(256), 0, stream>>>(hidden, W_hh, pre, hb, act,
                                            out + (size_t)B_ * S_ * V_, bar);
  k_gemm_dec<<<dim3(V_ / 128, (B_ * S_) / 128), dim3(256), 0, stream>>>(
      act, wdec16, b_dec, topic, stop, out);
}